// Round 7
// baseline (11358.954 us; speedup 1.0000x reference)
//
#include <hip/hip_runtime.h>

#define T_STEPS 4096
#define HD 2048
#define G4 8192
#define NWG 256
#define NTH 512
#define HSENT2 0xFF80FF80u

#define HB_OFF  131072                    // weights 128 KB, then h dbl-buf 2x4KB
#define P_OFF   (131072 + 8192)           // partials: 2 x (32 rows x 8 waves) f32
#define SMEM_BYTES (131072 + 8192 + 2048)

typedef __attribute__((ext_vector_type(8))) short bf16x8;
typedef __attribute__((ext_vector_type(4))) float f32x4;
typedef __attribute__((ext_vector_type(8))) unsigned short u16x8;

static __device__ __forceinline__ unsigned short f2bf(float f){
  union { float f; unsigned int u; } v; v.f = f;
  unsigned int r = (v.u + 0x7fffu + ((v.u >> 16) & 1u)) >> 16;
  return (unsigned short)r;
}
static __device__ __forceinline__ float bf2f(unsigned short s){
  union { unsigned int u; float f; } v; v.u = ((unsigned int)s) << 16;
  return v.f;
}
// write-through 2B store
static __device__ __forceinline__ void st2_uc(unsigned short* p, unsigned int v){
  asm volatile("global_store_short %0, %1, off sc0 sc1" :: "v"(p), "v"(v) : "memory");
}

// Spread-sampled poll of one 512B span of the h row into LDS.
// 4 rounds in flight (2 x global_load_lds_dword each), spaced by s_sleep ->
// detect delay ~ RT + ~150cyc instead of RT + U[0,RT]. Samples land in LDS so
// in-flight leftovers after detect are harmless (rewrite same bytes: sampling
// times are monotone in issue order, values write-once). la/lb = ABSOLUTE LDS
// byte offsets (dynamic LDS assumed at 0: no static __shared__ in kernel);
// chk = per-lane LDS byte addr. Entry vmcnt(0) drains prior XP/publish ops so
// counted vmcnt(6) is exact.
static __device__ __forceinline__ void poll_span(const unsigned int* ga, const unsigned int* gb,
                                                 unsigned la, unsigned lb, unsigned chk){
  unsigned t0, t1;
  asm volatile(
    "s_waitcnt vmcnt(0)\n\t"
    "s_mov_b32 m0, %[la]\n\t"
    "global_load_lds_dword %[ga], off sc0 sc1\n\t"
    "s_mov_b32 m0, %[lb]\n\t"
    "global_load_lds_dword %[gb], off sc0 sc1\n\t"
    "s_sleep 2\n\t"
    "s_mov_b32 m0, %[la]\n\t"
    "global_load_lds_dword %[ga], off sc0 sc1\n\t"
    "s_mov_b32 m0, %[lb]\n\t"
    "global_load_lds_dword %[gb], off sc0 sc1\n\t"
    "s_sleep 2\n\t"
    "s_mov_b32 m0, %[la]\n\t"
    "global_load_lds_dword %[ga], off sc0 sc1\n\t"
    "s_mov_b32 m0, %[lb]\n\t"
    "global_load_lds_dword %[gb], off sc0 sc1\n\t"
    "s_sleep 2\n\t"
    "s_mov_b32 m0, %[la]\n\t"
    "global_load_lds_dword %[ga], off sc0 sc1\n\t"
    "s_mov_b32 m0, %[lb]\n\t"
    "global_load_lds_dword %[gb], off sc0 sc1\n\t"
    "s_mov_b32 m0, -1\n\t"
    "Lpoll%=:\n\t"
    "s_waitcnt vmcnt(6)\n\t"
    "ds_read_b32 %[t0], %[chk]\n\t"
    "ds_read_b32 %[t1], %[chk] offset:256\n\t"
    "s_waitcnt lgkmcnt(0)\n\t"
    "v_xor_b32 %[t0], 0xff80ff80, %[t0]\n\t"
    "v_xor_b32 %[t1], 0xff80ff80, %[t1]\n\t"
    "v_min_u32 %[t0], %[t0], %[t1]\n\t"
    "v_cmp_eq_u32 vcc, 0, %[t0]\n\t"
    "s_cbranch_vccz Ldone%=\n\t"
    "s_mov_b32 m0, %[la]\n\t"
    "global_load_lds_dword %[ga], off sc0 sc1\n\t"
    "s_mov_b32 m0, %[lb]\n\t"
    "global_load_lds_dword %[gb], off sc0 sc1\n\t"
    "s_mov_b32 m0, -1\n\t"
    "s_sleep 2\n\t"
    "s_branch Lpoll%=\n\t"
    "Ldone%=:\n\t"
    : [t0]"=&v"(t0), [t1]"=&v"(t1)
    : [ga]"v"(ga), [gb]"v"(gb), [la]"s"(la), [lb]"s"(lb), [chk]"v"(chk)
    : "vcc", "memory");
}

// ---------------- init: bias fuse + h0 zeros + sentinel rows (bf16) ----------------
__global__ void init_kernel(const float* __restrict__ b_ih, const float* __restrict__ b_hh,
                            float* __restrict__ bias, unsigned int* __restrict__ Hb32){
  int i = blockIdx.x*blockDim.x + threadIdx.x;
  int stride = gridDim.x*blockDim.x;
  const int HB_U32 = (T_STEPS+1)*HD/2;
  const int NTOT = G4 + HB_U32;
  for (int idx = i; idx < NTOT; idx += stride){
    if (idx < G4) bias[idx] = b_ih[idx] + b_hh[idx];
    else {
      int j = idx - G4;
      Hb32[j] = (j < HD/2) ? 0u : HSENT2;   // row 0 = bf16 zeros, rest sentinel
    }
  }
}

// ---------------- phase 1: XP = x @ W_ih^T + (b_ih+b_hh), bf16 out ----------------
__global__ __launch_bounds__(256) void gemm_xp(const float* __restrict__ X,
                                               const float* __restrict__ W,
                                               const float* __restrict__ bias,
                                               unsigned short* __restrict__ XP){
  __shared__ __align__(16) unsigned short As[128][40];
  __shared__ __align__(16) unsigned short Bs[128][40];
  const int tid = threadIdx.x;
  const int bx = blockIdx.x & 63;
  const int by = blockIdx.x >> 6;
  const int row0 = by*128, col0 = bx*128;
  const int l = tid & 63, w = tid >> 6;
  const int wrow = (w>>1)*64, wcol = (w&1)*64;
  const int lr = l & 15, lk = l >> 4;

  f32x4 acc[4][4];
  #pragma unroll
  for (int mi=0; mi<4; mi++)
    #pragma unroll
    for (int ni=0; ni<4; ni++)
      acc[mi][ni] = (f32x4){0.f,0.f,0.f,0.f};

  const int sr = tid >> 1;
  const int sh = (tid & 1) * 16;
  const float* xb = X + (size_t)(row0+sr)*2048 + sh;
  const float* wb = W + (size_t)(col0+sr)*2048 + sh;

  for (int k0 = 0; k0 < 2048; k0 += 32){
    __syncthreads();
    u16x8 va[2], vb[2];
    #pragma unroll
    for (int q=0; q<2; q++){
      float4 u = *(const float4*)(xb + k0 + q*8);
      float4 v = *(const float4*)(xb + k0 + q*8 + 4);
      u16x8 t;
      t[0]=f2bf(u.x); t[1]=f2bf(u.y); t[2]=f2bf(u.z); t[3]=f2bf(u.w);
      t[4]=f2bf(v.x); t[5]=f2bf(v.y); t[6]=f2bf(v.z); t[7]=f2bf(v.w);
      va[q]=t;
      float4 p = *(const float4*)(wb + k0 + q*8);
      float4 r = *(const float4*)(wb + k0 + q*8 + 4);
      u16x8 s;
      s[0]=f2bf(p.x); s[1]=f2bf(p.y); s[2]=f2bf(p.z); s[3]=f2bf(p.w);
      s[4]=f2bf(r.x); s[5]=f2bf(r.y); s[6]=f2bf(r.z); s[7]=f2bf(r.w);
      vb[q]=s;
    }
    *(u16x8*)&As[sr][sh]   = va[0];
    *(u16x8*)&As[sr][sh+8] = va[1];
    *(u16x8*)&Bs[sr][sh]   = vb[0];
    *(u16x8*)&Bs[sr][sh+8] = vb[1];
    __syncthreads();

    bf16x8 af[4], bfr[4];
    #pragma unroll
    for (int mi=0; mi<4; mi++) af[mi]  = *(const bf16x8*)&As[wrow+mi*16+lr][lk*8];
    #pragma unroll
    for (int ni=0; ni<4; ni++) bfr[ni] = *(const bf16x8*)&Bs[wcol+ni*16+lr][lk*8];
    #pragma unroll
    for (int mi=0; mi<4; mi++)
      #pragma unroll
      for (int ni=0; ni<4; ni++)
        acc[mi][ni] = __builtin_amdgcn_mfma_f32_16x16x32_bf16(af[mi], bfr[ni], acc[mi][ni], 0,0,0);
  }

  #pragma unroll
  for (int ni=0; ni<4; ni++){
    const int jc = col0 + wcol + ni*16 + lr;
    const float bv = bias[jc];
    #pragma unroll
    for (int mi=0; mi<4; mi++){
      const int tr0 = row0 + wrow + mi*16 + lk*4;
      #pragma unroll
      for (int r=0; r<4; r++)
        XP[(size_t)(tr0+r)*G4 + jc] = f2bf(acc[mi][ni][r] + bv);
    }
  }
}

// ---------------- phase 2: persistent LSTM recurrence ----------------
// 256 WGs x 512 thr (8 waves). WG g owns h-dims [8g,8g+8) = 32 gate rows
// (rr = gate*8+dd). Wave w covers K-slice [w*256,+256): 16 MFMAs/step.
// Weights: LDS, pre-swizzled B-frags (128 KB). h: spread-poll into LDS
// (poll_span), parity double-buffered. Partials: [row][wave] layout, parity
// double-buffered, ONE barrier/step. Cell: 32 lanes compute all gates'
// transcendentals in parallel (serial exp depth 2). Publish: 8-lane
// store_short (one instruction, one line).
__global__ __launch_bounds__(NTH, 1) void recur(const unsigned short* __restrict__ XP,
                                                const float* __restrict__ Whh,
                                                unsigned short* __restrict__ Hbuf){
  extern __shared__ char smem[];
  const int g = blockIdx.x;
  const int tid = threadIdx.x;
  const int l = tid & 63, w = tid >> 6;

  // ---- stage weights as pre-swizzled MFMA B-fragments ----
  #pragma unroll
  for (int n=0; n<2; n++)
    #pragma unroll
    for (int kt=0; kt<8; kt++){
      const int rr = n*16 + (l & 15);
      const size_t jrow = (size_t)(rr>>3)*HD + (size_t)g*8 + (rr&7);
      const int k = w*256 + kt*32 + (l>>4)*8;
      const float* wp = Whh + jrow*HD + k;
      float4 fa = *(const float4*)wp;
      float4 fb = *(const float4*)(wp + 4);
      uint4 pk;
      pk.x = ((unsigned)f2bf(fa.y)<<16) | f2bf(fa.x);
      pk.y = ((unsigned)f2bf(fa.w)<<16) | f2bf(fa.z);
      pk.z = ((unsigned)f2bf(fb.y)<<16) | f2bf(fb.x);
      pk.w = ((unsigned)f2bf(fb.w)<<16) | f2bf(fb.z);
      *(uint4*)(smem + (size_t)(((w*16 + n*8 + kt)*64 + l)*16)) = pk;
    }
  __syncthreads();

  float c_reg = 0.f;     // cell state (wave 0, lanes 0..7)
  float xpv = 0.f;       // per-lane gate preact input (wave 0, lanes 0..31)
  if (w == 0 && l < 32)
    xpv = bf2f(XP[(size_t)(l>>3)*HD + (size_t)g*8 + (l&7)]);

  for (int t=0; t<T_STEPS; ++t){
    const int par = t & 1;
    // ---- spread-poll own span of h[t-1] (row t; row 0 = zeros) into LDS ----
    {
      const unsigned int* hrow = (const unsigned int*)(Hbuf + (size_t)t*HD);
      const unsigned int* ga = hrow + w*128 + l;
      const unsigned int* gb = ga + 64;
      unsigned la = (unsigned)__builtin_amdgcn_readfirstlane(HB_OFF + par*4096 + w*512);
      unsigned lb = la + 256;
      unsigned chk = la + l*4;
      poll_span(ga, gb, la, lb, chk);
    }
    const char* hb = smem + HB_OFF + par*4096 + w*512;

    // A-fragments: broadcast h (same addr within each 16-lane group)
    bf16x8 af[8];
    #pragma unroll
    for (int kt=0; kt<8; kt++)
      af[kt] = *(const bf16x8*)(hb + kt*64 + (l>>4)*16);

    f32x4 acc0 = (f32x4){0.f,0.f,0.f,0.f};
    f32x4 acc1 = (f32x4){0.f,0.f,0.f,0.f};
    #pragma unroll
    for (int kt=0; kt<8; kt++){
      bf16x8 b0 = *(const bf16x8*)(smem + (size_t)(((w*16 +     kt)*64 + l)*16));
      bf16x8 b1 = *(const bf16x8*)(smem + (size_t)(((w*16 + 8 + kt)*64 + l)*16));
      acc0 = __builtin_amdgcn_mfma_f32_16x16x32_bf16(af[kt], b0, acc0, 0,0,0);
      acc1 = __builtin_amdgcn_mfma_f32_16x16x32_bf16(af[kt], b1, acc1, 0,0,0);
    }
    // partials: [row][wave] layout (row = gate*8+dd), D row 0 = lanes 0..15 reg 0
    float* part = (float*)(smem + P_OFF + par*1024);
    if (l < 16){
      part[l*8 + w]      = acc0[0];
      part[(16+l)*8 + w] = acc1[0];
    }
    __syncthreads();

    // wave 0: reduce + parallel-lane cell + publish
    if (w == 0){
      __builtin_amdgcn_s_setprio(1);
      float act = 0.f;
      if (l < 32){
        float4 pa = *(const float4*)(part + l*8);
        float4 pb = *(const float4*)(part + l*8 + 4);
        float tot = ((pa.x+pa.y)+(pa.z+pa.w)) + ((pb.x+pb.y)+(pb.z+pb.w)) + xpv;
        const bool isg = ((l>>3) == 2);
        float z = __expf(isg ? -2.f*tot : -tot);
        float s = 1.f/(1.f + z);
        act = isg ? 2.f*s - 1.f : s;    // tanh via sigmoid identity for g-gate
      }
      float fv = __shfl_down(act, 8, 64);
      float gv = __shfl_down(act, 16, 64);
      float ov = __shfl_down(act, 24, 64);
      if (l < 8){
        c_reg = fv*c_reg + act*gv;      // act = i-gate on lanes 0..7
        float e2c = __expf(-2.f*c_reg);
        float th = (1.f - e2c)/(1.f + e2c);
        st2_uc(Hbuf + (size_t)(t+1)*HD + (size_t)g*8 + l, (unsigned)f2bf(ov*th));
      }
      __builtin_amdgcn_s_setprio(0);
      // preload next step's XP (off critical path)
      if (l < 32){
        const int tn = (t+1 < T_STEPS) ? t+1 : t;
        xpv = bf2f(XP[(size_t)tn*G4 + (size_t)(l>>3)*HD + (size_t)g*8 + (l&7)]);
      }
    }
  }
}

// ---------------- phase 3: y[t] = h_t . W_out + b_out (h is bf16) ----------------
__global__ __launch_bounds__(256) void out_gemv(const unsigned short* __restrict__ Hbuf,
                                                const float* __restrict__ Wout,
                                                const float* __restrict__ bout,
                                                float* __restrict__ y){
  const int t = blockIdx.x;
  const int tid = threadIdx.x;
  u16x8 hv = *(const u16x8*)(Hbuf + (size_t)(t+1)*HD + tid*8);
  float4 w0 = *(const float4*)(Wout + tid*8);
  float4 w1 = *(const float4*)(Wout + tid*8 + 4);
  float s = bf2f(hv[0])*w0.x + bf2f(hv[1])*w0.y + bf2f(hv[2])*w0.z + bf2f(hv[3])*w0.w
          + bf2f(hv[4])*w1.x + bf2f(hv[5])*w1.y + bf2f(hv[6])*w1.z + bf2f(hv[7])*w1.w;
  #pragma unroll
  for (int off=32; off; off>>=1) s += __shfl_xor(s, off, 64);
  __shared__ float ps[4];
  if ((tid & 63) == 0) ps[tid>>6] = s;
  __syncthreads();
  if (tid == 0) y[t] = ps[0]+ps[1]+ps[2]+ps[3] + bout[0];
}

extern "C" void kernel_launch(void* const* d_in, const int* in_sizes, int n_in,
                              void* d_out, int out_size, void* d_ws, size_t ws_size,
                              hipStream_t stream) {
  const float* x    = (const float*)d_in[0];
  const float* Wih  = (const float*)d_in[1];
  const float* Whh  = (const float*)d_in[2];
  const float* b_ih = (const float*)d_in[3];
  const float* b_hh = (const float*)d_in[4];
  const float* Wout = (const float*)d_in[5];
  const float* bout = (const float*)d_in[6];
  float* y = (float*)d_out;

  char* ws = (char*)d_ws;
  unsigned short* XP   = (unsigned short*)(ws);               // 4096*8192*2   = 67108864
  unsigned short* Hbuf = (unsigned short*)(ws + 67108864);    // 4097*2048*2   = 16781312
  float* bias          = (float*)(ws + 83890176);             // 8192*4        = 32768

  init_kernel<<<2048, 256, 0, stream>>>(b_ih, b_hh, bias, (unsigned int*)Hbuf);
  gemm_xp<<<2048, 256, 0, stream>>>(x, Wih, bias, XP);

  hipFuncSetAttribute((const void*)recur,
                      hipFuncAttributeMaxDynamicSharedMemorySize, SMEM_BYTES);
  void* args[] = {(void*)&XP, (void*)&Whh, (void*)&Hbuf};
  hipLaunchCooperativeKernel((void*)recur, dim3(NWG), dim3(NTH), args,
                             SMEM_BYTES, stream);

  out_gemv<<<T_STEPS, 256, 0, stream>>>(Hbuf, Wout, bout, y);
}

// Round 8
// 10278.245 us; speedup vs baseline: 1.1051x; 1.1051x over previous
//
#include <hip/hip_runtime.h>

#define T_STEPS 4096
#define HD 2048
#define G4 8192
#define NWG 256
#define NTH 512
#define HSENT2 0xFF80FF80u

#define HB_OFF  131072                    // weights 128 KB, then h spans 4 KB
#define P_OFF   (131072 + 4096)           // partials: 2 x (8 waves x 32) f32 = 2 KB
#define SMEM_BYTES (131072 + 4096 + 2048)

typedef __attribute__((ext_vector_type(8))) short bf16x8;
typedef __attribute__((ext_vector_type(4))) float f32x4;
typedef __attribute__((ext_vector_type(8))) unsigned short u16x8;
typedef __attribute__((ext_vector_type(2))) unsigned int u32x2;

static __device__ __forceinline__ unsigned short f2bf(float f){
  union { float f; unsigned int u; } v; v.f = f;
  unsigned int r = (v.u + 0x7fffu + ((v.u >> 16) & 1u)) >> 16;
  return (unsigned short)r;
}
static __device__ __forceinline__ float bf2f(unsigned short s){
  union { unsigned int u; float f; } v; v.u = ((unsigned int)s) << 16;
  return v.f;
}

// DEVICE-scope (sc1 only) 8B load: bypasses L1/L2, served by Infinity Cache
// (the device coherence point). NOT sc0 sc1 = system scope = DRAM — that was
// the R2-R7 2.5us/step floor (FETCH_SIZE showed ~430MB of poll traffic @ HBM).
static __device__ __forceinline__ u32x2 ld2_dev(const unsigned int* p){
  u32x2 r;
  asm volatile("global_load_dwordx2 %0, %1, off sc1\n\ts_waitcnt vmcnt(0)"
               : "=v"(r) : "v"(p) : "memory");
  return r;
}
// DEVICE-scope write-through 2B store (publish h; stops at MALL)
static __device__ __forceinline__ void st2_dev(unsigned short* p, unsigned int v){
  asm volatile("global_store_short %0, %1, off sc1" :: "v"(p), "v"(v) : "memory");
}

// ---------------- init: bias fuse + h0 zeros + sentinel rows (bf16) ----------------
__global__ void init_kernel(const float* __restrict__ b_ih, const float* __restrict__ b_hh,
                            float* __restrict__ bias, unsigned int* __restrict__ Hb32){
  int i = blockIdx.x*blockDim.x + threadIdx.x;
  int stride = gridDim.x*blockDim.x;
  const int HB_U32 = (T_STEPS+1)*HD/2;
  const int NTOT = G4 + HB_U32;
  for (int idx = i; idx < NTOT; idx += stride){
    if (idx < G4) bias[idx] = b_ih[idx] + b_hh[idx];
    else {
      int j = idx - G4;
      Hb32[j] = (j < HD/2) ? 0u : HSENT2;   // row 0 = bf16 zeros, rest sentinel
    }
  }
}

// ---------------- phase 1: XP = x @ W_ih^T + (b_ih+b_hh), bf16 out ----------------
__global__ __launch_bounds__(256) void gemm_xp(const float* __restrict__ X,
                                               const float* __restrict__ W,
                                               const float* __restrict__ bias,
                                               unsigned short* __restrict__ XP){
  __shared__ __align__(16) unsigned short As[128][40];
  __shared__ __align__(16) unsigned short Bs[128][40];
  const int tid = threadIdx.x;
  const int bx = blockIdx.x & 63;
  const int by = blockIdx.x >> 6;
  const int row0 = by*128, col0 = bx*128;
  const int l = tid & 63, w = tid >> 6;
  const int wrow = (w>>1)*64, wcol = (w&1)*64;
  const int lr = l & 15, lk = l >> 4;

  f32x4 acc[4][4];
  #pragma unroll
  for (int mi=0; mi<4; mi++)
    #pragma unroll
    for (int ni=0; ni<4; ni++)
      acc[mi][ni] = (f32x4){0.f,0.f,0.f,0.f};

  const int sr = tid >> 1;
  const int sh = (tid & 1) * 16;
  const float* xb = X + (size_t)(row0+sr)*2048 + sh;
  const float* wb = W + (size_t)(col0+sr)*2048 + sh;

  for (int k0 = 0; k0 < 2048; k0 += 32){
    __syncthreads();
    u16x8 va[2], vb[2];
    #pragma unroll
    for (int q=0; q<2; q++){
      float4 u = *(const float4*)(xb + k0 + q*8);
      float4 v = *(const float4*)(xb + k0 + q*8 + 4);
      u16x8 t;
      t[0]=f2bf(u.x); t[1]=f2bf(u.y); t[2]=f2bf(u.z); t[3]=f2bf(u.w);
      t[4]=f2bf(v.x); t[5]=f2bf(v.y); t[6]=f2bf(v.z); t[7]=f2bf(v.w);
      va[q]=t;
      float4 p = *(const float4*)(wb + k0 + q*8);
      float4 r = *(const float4*)(wb + k0 + q*8 + 4);
      u16x8 s;
      s[0]=f2bf(p.x); s[1]=f2bf(p.y); s[2]=f2bf(p.z); s[3]=f2bf(p.w);
      s[4]=f2bf(r.x); s[5]=f2bf(r.y); s[6]=f2bf(r.z); s[7]=f2bf(r.w);
      vb[q]=s;
    }
    *(u16x8*)&As[sr][sh]   = va[0];
    *(u16x8*)&As[sr][sh+8] = va[1];
    *(u16x8*)&Bs[sr][sh]   = vb[0];
    *(u16x8*)&Bs[sr][sh+8] = vb[1];
    __syncthreads();

    bf16x8 af[4], bfr[4];
    #pragma unroll
    for (int mi=0; mi<4; mi++) af[mi]  = *(const bf16x8*)&As[wrow+mi*16+lr][lk*8];
    #pragma unroll
    for (int ni=0; ni<4; ni++) bfr[ni] = *(const bf16x8*)&Bs[wcol+ni*16+lr][lk*8];
    #pragma unroll
    for (int mi=0; mi<4; mi++)
      #pragma unroll
      for (int ni=0; ni<4; ni++)
        acc[mi][ni] = __builtin_amdgcn_mfma_f32_16x16x32_bf16(af[mi], bfr[ni], acc[mi][ni], 0,0,0);
  }

  #pragma unroll
  for (int ni=0; ni<4; ni++){
    const int jc = col0 + wcol + ni*16 + lr;
    const float bv = bias[jc];
    #pragma unroll
    for (int mi=0; mi<4; mi++){
      const int tr0 = row0 + wrow + mi*16 + lk*4;
      #pragma unroll
      for (int r=0; r<4; r++)
        XP[(size_t)(tr0+r)*G4 + jc] = f2bf(acc[mi][ni][r] + bv);
    }
  }
}

// ---------------- phase 2: persistent LSTM recurrence (MFMA, 8 waves) ----------------
// 256 WGs x 512 thr. WG g owns h-dims [8g,8g+8) = 32 gate rows (rr=gate*8+dd).
// Wave w covers K-slice [w*256,+256): polls ONLY its own 512B span of the h
// row (device-scope loads), writes it to its private LDS region (no barrier:
// same-wave lgkmcnt ordering), 16 MFMAs with LDS-resident pre-swizzled B-frag
// weights, partial write, ONE barrier, wave 0 reduces + parallel-lane cell +
// 8-lane device-scope publish. part[] parity-double-buffered so waves may run
// a step ahead. Sentinel 0xFF80 (bf16 -inf) unreachable since |h|<1.
__global__ __launch_bounds__(NTH, 1) void recur(const unsigned short* __restrict__ XP,
                                                const float* __restrict__ Whh,
                                                unsigned short* __restrict__ Hbuf){
  extern __shared__ char smem[];
  char* hb = smem + HB_OFF;
  const int g = blockIdx.x;
  const int tid = threadIdx.x;
  const int l = tid & 63, w = tid >> 6;

  // ---- stage weights as pre-swizzled MFMA B-fragments (128 KB LDS) ----
  // block idx = w*16 + n*8 + kt; lane l holds B[col=n*16+(l&15)][k=(l>>4)*8..+8]
  #pragma unroll
  for (int n=0; n<2; n++)
    #pragma unroll
    for (int kt=0; kt<8; kt++){
      const int rr = n*16 + (l & 15);
      const size_t jrow = (size_t)(rr>>3)*HD + (size_t)g*8 + (rr&7);
      const int k = w*256 + kt*32 + (l>>4)*8;
      const float* wp = Whh + jrow*HD + k;
      float4 fa = *(const float4*)wp;
      float4 fb = *(const float4*)(wp + 4);
      uint4 pk;
      pk.x = ((unsigned)f2bf(fa.y)<<16) | f2bf(fa.x);
      pk.y = ((unsigned)f2bf(fa.w)<<16) | f2bf(fa.z);
      pk.z = ((unsigned)f2bf(fb.y)<<16) | f2bf(fb.x);
      pk.w = ((unsigned)f2bf(fb.w)<<16) | f2bf(fb.z);
      *(uint4*)(smem + (size_t)(((w*16 + n*8 + kt)*64 + l)*16)) = pk;
    }
  __syncthreads();

  float c_reg = 0.f;     // cell state (wave 0, lanes 0..7)
  float xpv = 0.f;       // gate preact input (wave 0, lanes 0..31)
  if (w == 0 && l < 32)
    xpv = bf2f(XP[(size_t)(l>>3)*HD + (size_t)g*8 + (l&7)]);

  for (int t=0; t<T_STEPS; ++t){
    // ---- poll own span of h[t-1] (row t; row 0 = zeros), device scope ----
    u32x2 hv;
    {
      const unsigned int* hp = (const unsigned int*)(Hbuf + (size_t)t*HD) + w*128 + l*2;
      do { hv = ld2_dev(hp); }
      while (hv[0] == HSENT2 || hv[1] == HSENT2);
    }
    *(u32x2*)(hb + w*512 + l*8) = hv;

    // A-fragments: broadcast h (same addr within each 16-lane group)
    bf16x8 af[8];
    #pragma unroll
    for (int kt=0; kt<8; kt++)
      af[kt] = *(const bf16x8*)(hb + w*512 + kt*64 + (l>>4)*16);

    f32x4 acc0 = (f32x4){0.f,0.f,0.f,0.f};
    f32x4 acc1 = (f32x4){0.f,0.f,0.f,0.f};
    #pragma unroll
    for (int kt=0; kt<8; kt++){
      bf16x8 b0 = *(const bf16x8*)(smem + (size_t)(((w*16 +     kt)*64 + l)*16));
      bf16x8 b1 = *(const bf16x8*)(smem + (size_t)(((w*16 + 8 + kt)*64 + l)*16));
      acc0 = __builtin_amdgcn_mfma_f32_16x16x32_bf16(af[kt], b0, acc0, 0,0,0);
      acc1 = __builtin_amdgcn_mfma_f32_16x16x32_bf16(af[kt], b1, acc1, 0,0,0);
    }
    // partials: [wave][row] layout (conflict-free), parity double-buffered
    float* part = (float*)(smem + P_OFF) + (t&1)*256;
    if (l < 16){
      part[w*32 + l]      = acc0[0];
      part[w*32 + 16 + l] = acc1[0];
    }
    __syncthreads();

    // wave 0: reduce + parallel-lane cell + publish
    if (w == 0){
      __builtin_amdgcn_s_setprio(1);
      float act = 0.f;
      if (l < 32){
        float tot = xpv;
        #pragma unroll
        for (int q=0; q<8; q++) tot += part[q*32 + l];
        const bool isg = ((l>>3) == 2);
        float z = __expf(isg ? -2.f*tot : -tot);
        float s = 1.f/(1.f + z);
        act = isg ? 2.f*s - 1.f : s;    // tanh via sigmoid identity for g-gate
      }
      float fv = __shfl_down(act, 8, 64);
      float gv = __shfl_down(act, 16, 64);
      float ov = __shfl_down(act, 24, 64);
      if (l < 8){
        c_reg = fv*c_reg + act*gv;      // act = i-gate on lanes 0..7
        float e2c = __expf(-2.f*c_reg);
        float th = (1.f - e2c)/(1.f + e2c);
        st2_dev(Hbuf + (size_t)(t+1)*HD + (size_t)g*8 + l, (unsigned)f2bf(ov*th));
      }
      __builtin_amdgcn_s_setprio(0);
      // preload next step's XP (off critical path)
      if (l < 32){
        const int tn = (t+1 < T_STEPS) ? t+1 : t;
        xpv = bf2f(XP[(size_t)tn*G4 + (size_t)(l>>3)*HD + (size_t)g*8 + (l&7)]);
      }
    }
  }
}

// ---------------- phase 3: y[t] = h_t . W_out + b_out (h is bf16) ----------------
__global__ __launch_bounds__(256) void out_gemv(const unsigned short* __restrict__ Hbuf,
                                                const float* __restrict__ Wout,
                                                const float* __restrict__ bout,
                                                float* __restrict__ y){
  const int t = blockIdx.x;
  const int tid = threadIdx.x;
  u16x8 hv = *(const u16x8*)(Hbuf + (size_t)(t+1)*HD + tid*8);
  float4 w0 = *(const float4*)(Wout + tid*8);
  float4 w1 = *(const float4*)(Wout + tid*8 + 4);
  float s = bf2f(hv[0])*w0.x + bf2f(hv[1])*w0.y + bf2f(hv[2])*w0.z + bf2f(hv[3])*w0.w
          + bf2f(hv[4])*w1.x + bf2f(hv[5])*w1.y + bf2f(hv[6])*w1.z + bf2f(hv[7])*w1.w;
  #pragma unroll
  for (int off=32; off; off>>=1) s += __shfl_xor(s, off, 64);
  __shared__ float ps[4];
  if ((tid & 63) == 0) ps[tid>>6] = s;
  __syncthreads();
  if (tid == 0) y[t] = ps[0]+ps[1]+ps[2]+ps[3] + bout[0];
}

extern "C" void kernel_launch(void* const* d_in, const int* in_sizes, int n_in,
                              void* d_out, int out_size, void* d_ws, size_t ws_size,
                              hipStream_t stream) {
  const float* x    = (const float*)d_in[0];
  const float* Wih  = (const float*)d_in[1];
  const float* Whh  = (const float*)d_in[2];
  const float* b_ih = (const float*)d_in[3];
  const float* b_hh = (const float*)d_in[4];
  const float* Wout = (const float*)d_in[5];
  const float* bout = (const float*)d_in[6];
  float* y = (float*)d_out;

  char* ws = (char*)d_ws;
  unsigned short* XP   = (unsigned short*)(ws);               // 4096*8192*2   = 67108864
  unsigned short* Hbuf = (unsigned short*)(ws + 67108864);    // 4097*2048*2   = 16781312
  float* bias          = (float*)(ws + 83890176);             // 8192*4        = 32768

  init_kernel<<<2048, 256, 0, stream>>>(b_ih, b_hh, bias, (unsigned int*)Hbuf);
  gemm_xp<<<2048, 256, 0, stream>>>(x, Wih, bias, XP);

  hipFuncSetAttribute((const void*)recur,
                      hipFuncAttributeMaxDynamicSharedMemorySize, SMEM_BYTES);
  void* args[] = {(void*)&XP, (void*)&Whh, (void*)&Hbuf};
  hipLaunchCooperativeKernel((void*)recur, dim3(NWG), dim3(NTH), args,
                             SMEM_BYTES, stream);

  out_gemv<<<T_STEPS, 256, 0, stream>>>(Hbuf, Wout, bout, y);
}